// Round 8
// baseline (1518.164 us; speedup 1.0000x reference)
//
#include <hip/hip_runtime.h>
#include <hip/hip_bf16.h>

typedef _Float16 half8_t __attribute__((ext_vector_type(8)));
typedef _Float16 half4_t __attribute__((ext_vector_type(4)));
typedef _Float16 half2_t __attribute__((ext_vector_type(2)));
typedef float float4_t __attribute__((ext_vector_type(4)));

#define TT 1024
#define BB 128
#define EE 128
#define HH 128
#define NTAG 64
#define ASTR 144  // LDS row stride (f16); 136 doubled conflicts (R7), 144 is the measured-better residue

__device__ __forceinline__ float fast_exp(float x) {
  return __builtin_amdgcn_exp2f(x * 1.44269504088896f);
}
// LDS-only barrier: does NOT drain vmcnt -> global loads/stores stay in flight.
__device__ __forceinline__ void lds_barrier() {
  asm volatile("s_waitcnt lgkmcnt(0)\n\ts_barrier" ::: "memory");
}
// Single-wave LDS write->read fence.
__device__ __forceinline__ void lds_fence() {
  asm volatile("s_waitcnt lgkmcnt(0)" ::: "memory");
}
__device__ __forceinline__ half2_t cvt_pk(float a, float b) {
  return __builtin_bit_cast(half2_t, __builtin_amdgcn_cvt_pkrtz(a, b));
}
__device__ __forceinline__ half2_t h2bc(float v) {
  _Float16 h = (_Float16)v;
  half2_t r; r[0] = h; r[1] = h;
  return r;
}
// deg-5 odd poly tanh: a0=1, fit at x=1,1.6; clamp +-1.6.
__device__ __forceinline__ half2_t tanh_p(half2_t x) {
  half2_t y = __builtin_elementwise_min(__builtin_elementwise_max(x, h2bc(-1.6f)), h2bc(1.6f));
  half2_t u = y * y;
  half2_t p = u * h2bc(0.04667f) + h2bc(-0.28507f);
  p = u * p + h2bc(1.0f);
  return y * p;
}
__device__ __forceinline__ half2_t sig_p(half2_t x) {
  half2_t y = __builtin_elementwise_min(
      __builtin_elementwise_max(x * h2bc(0.5f), h2bc(-1.6f)), h2bc(1.6f));
  half2_t u = y * y;
  half2_t p = u * h2bc(0.04667f) + h2bc(-0.28507f);
  p = u * p + h2bc(1.0f);
  return (y * p) * h2bc(0.5f) + h2bc(0.5f);
}

// ---------------------------------------------------------------- init: zero LSTM state
__global__ __launch_bounds__(256) void init_kernel(float4_t* __restrict__ p) {
  p[blockIdx.x * 256 + threadIdx.x] = (float4_t){0.f, 0.f, 0.f, 0.f};
}

// ---------------------------------------------------------------- embed: x[t*B+b][e] f16
__global__ __launch_bounds__(256) void embed_kernel(const int* __restrict__ kmers,
                                                    const float* __restrict__ emb,
                                                    half4_t* __restrict__ x) {
  const int g = blockIdx.x * 256 + threadIdx.x;
  const int row = g >> 5, seg = g & 31;
  const int km = kmers[row];
  const float4_t v = ((const float4_t*)(emb + (size_t)km * EE))[seg];
  half4_t o;
  o[0] = (_Float16)v[0]; o[1] = (_Float16)v[1];
  o[2] = (_Float16)v[2]; o[3] = (_Float16)v[3];
  x[(size_t)row * 32 + seg] = o;
}

// ---------------------------------------------------------------- xg segment (W as A-operand)
// D[m=gate-row][n=batch], k=E. B-frags (x^T) loaded directly from global; no LDS.
// Output layout matches LSTM reader: dir*Tseg*65536 + l*65536 + (chunk*8+wave)*1024 + g*256 + lane*4 + r
__global__ __launch_bounds__(512) void xg_kernel(
    const _Float16* __restrict__ x,
    const float* __restrict__ w_ih_f, const float* __restrict__ b_ih_f, const float* __restrict__ b_hh_f,
    const float* __restrict__ w_ih_b, const float* __restrict__ b_ih_b, const float* __restrict__ b_hh_b,
    _Float16* __restrict__ xgbuf, int s, int Tseg) {
  const int nt = Tseg >> 4;           // t-blocks per (dir,chunk); TBLK = 16
  const int wg = blockIdx.x;          // grid = 2 * 8 * nt
  const int dir = wg / (8 * nt);
  const int rem = wg - dir * 8 * nt;
  const int chunk = rem / nt;
  const int tb = rem - chunk * nt;
  const int tid = threadIdx.x;
  const int wave = tid >> 6, lane = tid & 63;
  const int n16 = lane & 15, quad = lane >> 4;

  const float* wih = dir ? w_ih_b : w_ih_f;
  const float* bih = dir ? b_ih_b : b_ih_f;
  const float* bhh = dir ? b_hh_b : b_hh_f;

  // A-frags of W_ih: lane holds W[g*128 + wave*16 + n16][kf*32 + quad*8 + j]
  half8_t wf[4][4];
#pragma unroll
  for (int g = 0; g < 4; ++g) {
    const int row = g * HH + wave * 16 + n16;
#pragma unroll
    for (int kf = 0; kf < 4; ++kf) {
      const float* src = wih + row * EE + kf * 32 + quad * 8;
#pragma unroll
      for (int i = 0; i < 8; ++i) wf[g][kf][i] = (_Float16)src[i];
    }
  }
  // bias as C-init: rows m = quad*4+r -> hu = wave*16+quad*4+r
  float4_t bias4[4];
#pragma unroll
  for (int g = 0; g < 4; ++g) {
    const int row = g * HH + wave * 16 + quad * 4;
    const float4_t bi = *(const float4_t*)(bih + row);
    const float4_t bh = *(const float4_t*)(bhh + row);
    bias4[g] = bi + bh;
  }

  for (int u = 0; u < 16; ++u) {
    const int l = tb * 16 + u;  // t_loc in segment processing order
    const int te = dir ? (TT - 1 - (s * Tseg + l)) : (s * Tseg + l);
    // B-frags: x^T[k=e][n=batch] — lane reads 8 contiguous e at batch chunk*16+n16
    half8_t xb[4];
#pragma unroll
    for (int kf = 0; kf < 4; ++kf)
      xb[kf] = *(const half8_t*)(x + ((size_t)te * BB + chunk * 16 + n16) * EE + kf * 32 + quad * 8);
    float4_t acc[4];
#pragma unroll
    for (int g = 0; g < 4; ++g) acc[g] = bias4[g];
#pragma unroll
    for (int kf = 0; kf < 4; ++kf)
#pragma unroll
      for (int g = 0; g < 4; ++g)
        acc[g] = __builtin_amdgcn_mfma_f32_16x16x32_f16(wf[g][kf], xb[kf], acc[g], 0, 0, 0);
    _Float16* ob = xgbuf + (size_t)dir * Tseg * 65536 + (size_t)l * 65536 +
                   (chunk * 8 + wave) * 1024 + lane * 4;
#pragma unroll
    for (int g = 0; g < 4; ++g) {
      half4_t o;
#pragma unroll
      for (int r = 0; r < 4; ++r) o[r] = (_Float16)acc[g][r];
      *(half4_t*)(ob + g * 256) = o;
    }
  }
}

// ---------------------------------------------------------------- bidirectional LSTM segment
// Transposed orientation: A = W_hh (regs), B = h^T (LDS), D[m=gate-row][n=batch].
// Lane's outputs = 4 contiguous hu at one batch -> 1 ds_write_b64 + 1 8B global store.
__global__ __launch_bounds__(512, 2) void lstm_kernel(
    const _Float16* __restrict__ xgbuf,
    const float* __restrict__ w_hh_f, const float* __restrict__ w_hh_b,
    _Float16* __restrict__ h_cat, _Float16* __restrict__ h_state, float* __restrict__ c_state,
    int s, int Tseg) {
  __shared__ _Float16 A[2][16 * ASTR];  // h panel: [batch 16][hu 128]
  const int wg = blockIdx.x;
  const int dir = wg >> 3, chunk = wg & 7;
  const int b0 = chunk * 16;
  const float* w_hh = dir ? w_hh_b : w_hh_f;
  const int tid = threadIdx.x;
  const int wave = tid >> 6, lane = tid & 63;
  const int n16 = lane & 15, quad = lane >> 4;

  // A-frags of W_hh: lane holds W[g*128 + wave*16 + n16][kf*32 + quad*8 + j]
  half8_t wf[4][4];
#pragma unroll
  for (int g = 0; g < 4; ++g) {
    const int row = g * HH + wave * 16 + n16;
#pragma unroll
    for (int kf = 0; kf < 4; ++kf) {
      const float* src = w_hh + row * HH + kf * 32 + quad * 8;
#pragma unroll
      for (int i = 0; i < 8; ++i) wf[g][kf][i] = (_Float16)src[i];
    }
  }
  // persistent state: lane holds h/c for hu = wave*16+quad*4+r, batch = b0+n16
  const int sidx = ((wg * 8 + wave) * 64 + lane) * 4;
  half4_t h4 = *(const half4_t*)(h_state + sidx);
  float4_t c4 = *(const float4_t*)(c_state + sidx);
  half2_t c2[2];
  c2[0] = cvt_pk(c4[0], c4[1]);
  c2[1] = cvt_pk(c4[2], c4[3]);
  *(half4_t*)(&A[0][n16 * ASTR + wave * 16 + quad * 4]) = h4;  // seed h_{-1}

  const _Float16* xgw = xgbuf + (size_t)dir * Tseg * 65536 + (chunk * 8 + wave) * 1024 + lane * 4;
  half4_t xv[4];
#pragma unroll
  for (int g = 0; g < 4; ++g) xv[g] = *(const half4_t*)(xgw + g * 256);
  half4_t hlast = h4;
  const float4_t z4 = {0.f, 0.f, 0.f, 0.f};
  lds_barrier();

  for (int il = 0; il < Tseg; ++il) {
    half4_t xn[4] = {};
    if (il + 1 < Tseg) {
#pragma unroll
      for (int g = 0; g < 4; ++g)
        xn[g] = *(const half4_t*)(xgw + (size_t)(il + 1) * 65536 + g * 256);
    }
    // xg -> f32 C-init (off critical path: xv loaded a step ahead)
    float4_t xg32[4];
#pragma unroll
    for (int g = 0; g < 4; ++g)
#pragma unroll
      for (int r = 0; r < 4; ++r) xg32[g][r] = (float)xv[g][r];
    lds_barrier();  // h_{t-1} ready in buf[il&1]; global ops stay in flight
    const _Float16* Ab = &A[il & 1][0];
    _Float16* An = &A[(il + 1) & 1][0];
    half8_t hb[4];  // B-frags: h^T[k=hu][n=batch]
#pragma unroll
    for (int kf = 0; kf < 4; ++kf)
      hb[kf] = *(const half8_t*)(Ab + n16 * ASTR + kf * 32 + quad * 8);
    float4_t accA[4], accB[4];
#pragma unroll
    for (int g = 0; g < 4; ++g) {
      accA[g] = __builtin_amdgcn_mfma_f32_16x16x32_f16(wf[g][0], hb[0], xg32[g], 0, 0, 0);
      accB[g] = __builtin_amdgcn_mfma_f32_16x16x32_f16(wf[g][2], hb[2], z4, 0, 0, 0);
    }
#pragma unroll
    for (int g = 0; g < 4; ++g) {
      accA[g] = __builtin_amdgcn_mfma_f32_16x16x32_f16(wf[g][1], hb[1], accA[g], 0, 0, 0);
      accB[g] = __builtin_amdgcn_mfma_f32_16x16x32_f16(wf[g][3], hb[3], accB[g], 0, 0, 0);
    }
    half2_t gp[2][4];
#pragma unroll
    for (int g = 0; g < 4; ++g) {
      const float4_t sg = accA[g] + accB[g];
      gp[0][g] = cvt_pk(sg[0], sg[1]);
      gp[1][g] = cvt_pk(sg[2], sg[3]);
    }
#pragma unroll
    for (int g = 0; g < 4; ++g) xv[g] = xn[g];
    const int i = s * Tseg + il;
    const int te = dir ? (TT - 1 - i) : i;
    half4_t hstore;
#pragma unroll
    for (int p = 0; p < 2; ++p) {
      const half2_t i_ = sig_p(gp[p][0]);
      const half2_t f_ = sig_p(gp[p][1]);
      const half2_t g_ = tanh_p(gp[p][2]);
      const half2_t o_ = sig_p(gp[p][3]);
      c2[p] = f_ * c2[p] + i_ * g_;
      const half2_t hh = o_ * tanh_p(c2[p]);
      hstore[2 * p] = hh[0];
      hstore[2 * p + 1] = hh[1];
    }
    *(half4_t*)(An + n16 * ASTR + wave * 16 + quad * 4) = hstore;  // one b64 LDS write
    *(half4_t*)(h_cat + ((size_t)te * BB + b0 + n16) * 256 + dir * HH + wave * 16 + quad * 4) =
        hstore;  // one 8B global store, fire-and-forget
    hlast = hstore;
  }
  *(half4_t*)(h_state + sidx) = hlast;
  c4[0] = (float)c2[0][0]; c4[1] = (float)c2[0][1];
  c4[2] = (float)c2[1][0]; c4[3] = (float)c2[1][1];
  *(float4_t*)(c_state + sidx) = c4;
}

// ---------------------------------------------------------------- emissions: em f32 + expem f16
__global__ __launch_bounds__(256) void emis_kernel(const _Float16* __restrict__ h_cat,
                                                   const float* __restrict__ w_proj,
                                                   const float* __restrict__ b_proj,
                                                   float* __restrict__ em,
                                                   _Float16* __restrict__ expem) {
  const int tid = threadIdx.x;
  const int wave = tid >> 6, lane = tid & 63;
  const int n16 = lane & 15, quad = lane >> 4;
  const size_t row0 = (size_t)blockIdx.x * 64 + wave * 16;

  half8_t bf[4][8];
#pragma unroll
  for (int nt = 0; nt < 4; ++nt) {
    const float* wp = w_proj + (nt * 16 + n16) * 256;
#pragma unroll
    for (int kf = 0; kf < 8; ++kf) {
      const int kb = kf * 32 + quad * 8;
#pragma unroll
      for (int i = 0; i < 8; ++i) bf[nt][kf][i] = (_Float16)wp[kb + i];
    }
  }
  float4_t acc[4];
#pragma unroll
  for (int nt = 0; nt < 4; ++nt) {
    const float bv = b_proj[nt * 16 + n16];
    acc[nt] = (float4_t){bv, bv, bv, bv};
  }
#pragma unroll
  for (int kf = 0; kf < 8; ++kf) {
    half8_t af = *(const half8_t*)(h_cat + (row0 + n16) * 256 + kf * 32 + quad * 8);
#pragma unroll
    for (int nt = 0; nt < 4; ++nt)
      acc[nt] = __builtin_amdgcn_mfma_f32_16x16x32_f16(af, bf[nt][kf], acc[nt], 0, 0, 0);
  }
#pragma unroll
  for (int nt = 0; nt < 4; ++nt)
#pragma unroll
    for (int r = 0; r < 4; ++r) {
      const size_t idx = (row0 + quad * 4 + r) * NTAG + nt * 16 + n16;
      em[idx] = acc[nt][r];
      expem[idx] = (_Float16)fast_exp(acc[nt][r]);
    }
}

// ---------------------------------------------------------------- CRF forward, scaled linear space
// alpha' = (alpha @ (exp(trans)/64)) * expem; renorm every 16 steps. expem prefetched 4 steps
// ahead (register ring) to cover cold/HBM latency (~900 cyc > one step's ~400 cyc).
__global__ __launch_bounds__(64) void crf_kernel(const float* __restrict__ em,
                                                 const _Float16* __restrict__ expem,
                                                 const float* __restrict__ trans,
                                                 const float* __restrict__ start_trans,
                                                 const float* __restrict__ end_trans,
                                                 float* __restrict__ denom) {
  __shared__ float tmp[4 * 68 + 4];
  const int lane = threadIdx.x;
  const int n16 = lane & 15, quad = lane >> 4;
  const int b = n16 & 3;
  const int gb = blockIdx.x * 4 + b;

  half8_t ef[4][2];  // exp(trans)*2^-6 in B-frag layout [nt][kf]
#pragma unroll
  for (int nt = 0; nt < 4; ++nt)
#pragma unroll
    for (int kf = 0; kf < 2; ++kf)
#pragma unroll
      for (int i = 0; i < 8; ++i)
        ef[nt][kf][i] =
            (_Float16)(fast_exp(trans[(kf * 32 + quad * 8 + i) * NTAG + nt * 16 + n16]) * 0.015625f);

  float sv[16], et[16];
#pragma unroll
  for (int kf = 0; kf < 2; ++kf) {
    const int j0 = kf * 32 + quad * 8;
    float4_t s0 = *(const float4_t*)(start_trans + j0);
    float4_t s1 = *(const float4_t*)(start_trans + j0 + 4);
    float4_t e0 = *(const float4_t*)(end_trans + j0);
    float4_t e1 = *(const float4_t*)(end_trans + j0 + 4);
    float4_t m0v = *(const float4_t*)(em + (size_t)gb * NTAG + j0);
    float4_t m1v = *(const float4_t*)(em + (size_t)gb * NTAG + j0 + 4);
#pragma unroll
    for (int i = 0; i < 4; ++i) {
      sv[kf * 8 + i] = s0[i] + m0v[i];
      sv[kf * 8 + 4 + i] = s1[i] + m1v[i];
      et[kf * 8 + i] = e0[i];
      et[kf * 8 + 4 + i] = e1[i];
    }
  }
  float m0;
  {
    float mx[8];
#pragma unroll
    for (int i = 0; i < 8; ++i) mx[i] = fmaxf(sv[i], sv[8 + i]);
#pragma unroll
    for (int i = 0; i < 4; ++i) mx[i] = fmaxf(mx[i], mx[4 + i]);
    m0 = fmaxf(fmaxf(mx[0], mx[1]), fmaxf(mx[2], mx[3]));
    m0 = fmaxf(m0, __shfl_xor(m0, 16, 64));
    m0 = fmaxf(m0, __shfl_xor(m0, 32, 64));
  }
  half8_t pa[2];  // alpha in A-frag layout, f16
#pragma unroll
  for (int kf = 0; kf < 2; ++kf)
#pragma unroll
    for (int i = 0; i < 8; ++i) pa[kf][i] = (_Float16)fast_exp(sv[kf * 8 + i] - m0);
  float lz2 = 0.f;
  const float4_t z4 = {0.f, 0.f, 0.f, 0.f};

  const _Float16* exb = expem + (size_t)gb * NTAG;
  half8_t gr0[4], gr1[4];  // 4-deep prefetch ring
#pragma unroll
  for (int d = 0; d < 4; ++d) {
    gr0[d] = *(const half8_t*)(exb + (size_t)(1 + d) * 8192 + quad * 8);
    gr1[d] = *(const half8_t*)(exb + (size_t)(1 + d) * 8192 + 32 + quad * 8);
  }

  for (int tb = 1; tb < TT; tb += 4) {
#pragma unroll
    for (int u = 0; u < 4; ++u) {
      const int t = tb + u;
      if (t < TT) {
        const half8_t gc0 = gr0[u], gc1 = gr1[u];
        if (t + 4 < TT) {
          gr0[u] = *(const half8_t*)(exb + (size_t)(t + 4) * 8192 + quad * 8);
          gr1[u] = *(const half8_t*)(exb + (size_t)(t + 4) * 8192 + 32 + quad * 8);
        }
        // 8 independent MFMAs (depth 1), then 4 f32x4 adds
        float4_t u0 = __builtin_amdgcn_mfma_f32_16x16x32_f16(pa[0], ef[0][0], z4, 0, 0, 0);
        float4_t u1 = __builtin_amdgcn_mfma_f32_16x16x32_f16(pa[0], ef[1][0], z4, 0, 0, 0);
        float4_t u2 = __builtin_amdgcn_mfma_f32_16x16x32_f16(pa[0], ef[2][0], z4, 0, 0, 0);
        float4_t u3 = __builtin_amdgcn_mfma_f32_16x16x32_f16(pa[0], ef[3][0], z4, 0, 0, 0);
        float4_t w0 = __builtin_amdgcn_mfma_f32_16x16x32_f16(pa[1], ef[0][1], z4, 0, 0, 0);
        float4_t w1 = __builtin_amdgcn_mfma_f32_16x16x32_f16(pa[1], ef[1][1], z4, 0, 0, 0);
        float4_t w2 = __builtin_amdgcn_mfma_f32_16x16x32_f16(pa[1], ef[2][1], z4, 0, 0, 0);
        float4_t w3 = __builtin_amdgcn_mfma_f32_16x16x32_f16(pa[1], ef[3][1], z4, 0, 0, 0);
        const float4_t a0 = u0 + w0, a1 = u1 + w1, a2 = u2 + w2, a3 = u3 + w3;
        const float4_t aq = (quad == 0) ? a0 : (quad == 1) ? a1 : (quad == 2) ? a2 : a3;
        tmp[0 * 68 + quad * 16 + n16] = aq[0];
        tmp[1 * 68 + quad * 16 + n16] = aq[1];
        tmp[2 * 68 + quad * 16 + n16] = aq[2];
        tmp[3 * 68 + quad * 16 + n16] = aq[3];
        lds_fence();
        const float4_t v0 = *(const float4_t*)(&tmp[b * 68 + quad * 8]);
        const float4_t v1 = *(const float4_t*)(&tmp[b * 68 + quad * 8 + 4]);
        const float4_t v2 = *(const float4_t*)(&tmp[b * 68 + 32 + quad * 8]);
        const float4_t v3 = *(const float4_t*)(&tmp[b * 68 + 32 + quad * 8 + 4]);
        half2_t* p0 = (half2_t*)&pa[0];
        half2_t* p1 = (half2_t*)&pa[1];
        const half2_t* g0 = (const half2_t*)&gc0;
        const half2_t* g1 = (const half2_t*)&gc1;
        p0[0] = cvt_pk(v0[0], v0[1]) * g0[0];
        p0[1] = cvt_pk(v0[2], v0[3]) * g0[1];
        p0[2] = cvt_pk(v1[0], v1[1]) * g0[2];
        p0[3] = cvt_pk(v1[2], v1[3]) * g0[3];
        p1[0] = cvt_pk(v2[0], v2[1]) * g1[0];
        p1[1] = cvt_pk(v2[2], v2[3]) * g1[1];
        p1[2] = cvt_pk(v3[0], v3[1]) * g1[2];
        p1[3] = cvt_pk(v3[2], v3[3]) * g1[3];
        if ((t & 15) == 0) {  // periodic renorm
          half2_t m2 = __builtin_elementwise_max(p0[0], p0[1]);
          m2 = __builtin_elementwise_max(m2, __builtin_elementwise_max(p0[2], p0[3]));
          m2 = __builtin_elementwise_max(m2, __builtin_elementwise_max(p1[0], p1[1]));
          m2 = __builtin_elementwise_max(m2, __builtin_elementwise_max(p1[2], p1[3]));
          float mm = fmaxf((float)m2[0], (float)m2[1]);
          mm = fmaxf(mm, __shfl_xor(mm, 16, 64));
          mm = fmaxf(mm, __shfl_xor(mm, 32, 64));
          lz2 += __builtin_amdgcn_logf(mm);  // log2
          const half2_t rc = h2bc(__builtin_amdgcn_rcpf(mm));
#pragma unroll
          for (int j = 0; j < 4; ++j) { p0[j] *= rc; p1[j] *= rc; }
        }
      }
    }
  }

  float w = 0.f;
#pragma unroll
  for (int kf = 0; kf < 2; ++kf)
#pragma unroll
    for (int i = 0; i < 8; ++i) w += (float)pa[kf][i] * fast_exp(et[kf * 8 + i]);
  w += __shfl_xor(w, 16, 64);
  w += __shfl_xor(w, 32, 64);
  if (lane < 4)
    denom[blockIdx.x * 4 + lane] =
        m0 + 0.693147180559945f * (lz2 + 6138.0f + __builtin_amdgcn_logf(w));
}

// ---------------------------------------------------------------- numerator
__global__ __launch_bounds__(256) void numer_kernel(const float* __restrict__ em,
                                                    const int* __restrict__ tags,
                                                    const float* __restrict__ trans,
                                                    const float* __restrict__ start_trans,
                                                    const float* __restrict__ end_trans,
                                                    float* __restrict__ num) {
  const int b = blockIdx.x;
  const int tg = tags[b];
  float acc = 0.f;
  for (int t = threadIdx.x; t < TT; t += 256)
    acc += em[((size_t)t * BB + b) * NTAG + tg];
#pragma unroll
  for (int off = 32; off > 0; off >>= 1) acc += __shfl_xor(acc, off, 64);
  __shared__ float red[4];
  if ((threadIdx.x & 63) == 0) red[threadIdx.x >> 6] = acc;
  __syncthreads();
  if (threadIdx.x == 0) {
    const float tot = red[0] + red[1] + red[2] + red[3];
    num[b] = start_trans[tg] + end_trans[tg] + 1023.0f * trans[tg * NTAG + tg] + tot;
  }
}

// ---------------------------------------------------------------- final
__global__ __launch_bounds__(128) void final_kernel(const float* __restrict__ denom,
                                                    const float* __restrict__ num,
                                                    float* __restrict__ out) {
  const int tid = threadIdx.x;
  float v = denom[tid] - num[tid];
#pragma unroll
  for (int off = 32; off > 0; off >>= 1) v += __shfl_xor(v, off, 64);
  __shared__ float red[2];
  if ((tid & 63) == 0) red[tid >> 6] = v;
  __syncthreads();
  if (tid == 0) out[0] = red[0] + red[1];
}

extern "C" void kernel_launch(void* const* d_in, const int* in_sizes, int n_in,
                              void* d_out, int out_size, void* d_ws, size_t ws_size,
                              hipStream_t stream) {
  const int* kmers = (const int*)d_in[0];
  const int* tags = (const int*)d_in[1];
  const float* emb = (const float*)d_in[2];
  const float* w_ih_f = (const float*)d_in[3];
  const float* w_hh_f = (const float*)d_in[4];
  const float* b_ih_f = (const float*)d_in[5];
  const float* b_hh_f = (const float*)d_in[6];
  const float* w_ih_b = (const float*)d_in[7];
  const float* w_hh_b = (const float*)d_in[8];
  const float* b_ih_b = (const float*)d_in[9];
  const float* b_hh_b = (const float*)d_in[10];
  const float* w_proj = (const float*)d_in[11];
  const float* b_proj = (const float*)d_in[12];
  const float* start_trans = (const float*)d_in[13];
  const float* end_trans = (const float*)d_in[14];
  const float* trans = (const float*)d_in[15];

  int nseg;
  if (ws_size >= 235078656ull) nseg = 2;
  else if (ws_size >= 167969792ull) nseg = 4;
  else if (ws_size >= 134415360ull) nseg = 8;
  else nseg = 16;
  const int Tseg = TT / nseg;
  const size_t xg_bytes = 268435456ull / (size_t)nseg;

  char* ws = (char*)d_ws;
  half4_t* x = (half4_t*)ws;                       // [0, 33.5M); em aliases after xg done
  _Float16* h_cat = (_Float16*)(ws + 33554432);    // [33.5M, 100.7M)
  _Float16* xgbuf = (_Float16*)(ws + 100663296);   // [100.7M, +xg_bytes)
  _Float16* expem = (_Float16*)(ws + 100663296);   // 16.8M, aliases xgbuf (dead after lstm)
  _Float16* h_state = (_Float16*)(ws + 100663296 + xg_bytes);    // 65,536 B
  float* c_state = (float*)(ws + 100663296 + xg_bytes + 65536);  // 131,072 B
  float* denom = (float*)(ws + 100663296 + xg_bytes + 196608);   // 512 B
  float* num = denom + 128;
  float* em = (float*)ws;
  float* out = (float*)d_out;

  hipLaunchKernelGGL(init_kernel, dim3(48), dim3(256), 0, stream, (float4_t*)h_state);
  hipLaunchKernelGGL(embed_kernel, dim3(16384), dim3(256), 0, stream, kmers, emb, x);
  for (int s = 0; s < nseg; ++s) {
    hipLaunchKernelGGL(xg_kernel, dim3(16 * (Tseg >> 4)), dim3(512), 0, stream,
                       (const _Float16*)x, w_ih_f, b_ih_f, b_hh_f, w_ih_b, b_ih_b, b_hh_b,
                       xgbuf, s, Tseg);
    hipLaunchKernelGGL(lstm_kernel, dim3(16), dim3(512), 0, stream, (const _Float16*)xgbuf,
                       w_hh_f, w_hh_b, h_cat, h_state, c_state, s, Tseg);
  }
  hipLaunchKernelGGL(emis_kernel, dim3(2048), dim3(256), 0, stream, h_cat, w_proj, b_proj, em,
                     expem);
  hipLaunchKernelGGL(crf_kernel, dim3(32), dim3(64), 0, stream, em, (const _Float16*)expem,
                     trans, start_trans, end_trans, denom);
  hipLaunchKernelGGL(numer_kernel, dim3(128), dim3(256), 0, stream, em, tags, trans, start_trans,
                     end_trans, num);
  hipLaunchKernelGGL(final_kernel, dim3(1), dim3(128), 0, stream, denom, num, out);
}

// Round 9
// 1455.416 us; speedup vs baseline: 1.0431x; 1.0431x over previous
//
#include <hip/hip_runtime.h>
#include <hip/hip_bf16.h>

typedef _Float16 half8_t __attribute__((ext_vector_type(8)));
typedef _Float16 half4_t __attribute__((ext_vector_type(4)));
typedef _Float16 half2_t __attribute__((ext_vector_type(2)));
typedef float float4_t __attribute__((ext_vector_type(4)));

#define TT 1024
#define BB 128
#define EE 128
#define HH 128
#define NTAG 64
#define ASTR 144  // R6-measured best stride (136 doubled conflicts in R7)

__device__ __forceinline__ float fast_exp(float x) {
  return __builtin_amdgcn_exp2f(x * 1.44269504088896f);
}
// LDS-only barrier: does NOT drain vmcnt -> global loads/stores stay in flight.
__device__ __forceinline__ void lds_barrier() {
  asm volatile("s_waitcnt lgkmcnt(0)\n\ts_barrier" ::: "memory");
}
// Single-wave LDS write->read fence.
__device__ __forceinline__ void lds_fence() {
  asm volatile("s_waitcnt lgkmcnt(0)" ::: "memory");
}
__device__ __forceinline__ half2_t cvt_pk(float a, float b) {
  return __builtin_bit_cast(half2_t, __builtin_amdgcn_cvt_pkrtz(a, b));
}
__device__ __forceinline__ half2_t h2bc(float v) {
  _Float16 h = (_Float16)v;
  half2_t r; r[0] = h; r[1] = h;
  return r;
}
// deg-5 odd tanh poly (fit at 1, 1.6; clamp +-1.6): 6 pk instrs
__device__ __forceinline__ half2_t tanh6(half2_t x) {
  half2_t y = __builtin_elementwise_min(__builtin_elementwise_max(x, h2bc(-1.6f)), h2bc(1.6f));
  half2_t u = y * y;
  half2_t p = u * h2bc(0.04667f) + h2bc(-0.28507f);
  p = u * p + h2bc(1.0f);
  return y * p;
}
// sigmoid with the x/2 scale folded into coefficients: 6 pk instrs
// sig(x) = 0.5 + xc*(0.25 + C3*xc^2 + C5*xc^4), xc = clamp(x, +-3.2)
__device__ __forceinline__ half2_t sig6(half2_t x) {
  half2_t y = __builtin_elementwise_min(__builtin_elementwise_max(x, h2bc(-3.2f)), h2bc(3.2f));
  half2_t u = y * y;
  half2_t q = u * h2bc(0.00072921875f) + h2bc(-0.017816875f);
  q = u * q + h2bc(0.25f);
  return y * q + h2bc(0.5f);
}

// ---------------------------------------------------------------- init: zero LSTM state
__global__ __launch_bounds__(256) void init_kernel(float4_t* __restrict__ p) {
  p[blockIdx.x * 256 + threadIdx.x] = (float4_t){0.f, 0.f, 0.f, 0.f};
}

// ---------------------------------------------------------------- embed: x[t*B+b][e] f16
__global__ __launch_bounds__(256) void embed_kernel(const int* __restrict__ kmers,
                                                    const float* __restrict__ emb,
                                                    half4_t* __restrict__ x) {
  const int g = blockIdx.x * 256 + threadIdx.x;
  const int row = g >> 5, seg = g & 31;
  const int km = kmers[row];
  const float4_t v = ((const float4_t*)(emb + (size_t)km * EE))[seg];
  half4_t o;
  o[0] = (_Float16)v[0]; o[1] = (_Float16)v[1];
  o[2] = (_Float16)v[2]; o[3] = (_Float16)v[3];
  x[(size_t)row * 32 + seg] = o;
}

// ---------------------------------------------------------------- xg segment (lane-major output)
// C rows = batch, cols = gate-row. A = x (direct b128 global loads), B = W_ih^T (regs).
// Output: dir*Tseg*65536 + l*65536 + chunk*8192 + wave*1024 + lane*16 + g*4 + r
__global__ __launch_bounds__(512) void xg_kernel(
    const _Float16* __restrict__ x,
    const float* __restrict__ w_ih_f, const float* __restrict__ b_ih_f, const float* __restrict__ b_hh_f,
    const float* __restrict__ w_ih_b, const float* __restrict__ b_ih_b, const float* __restrict__ b_hh_b,
    _Float16* __restrict__ xgbuf, int s, int Tseg) {
  const int nt = Tseg >> 4;
  const int wg = blockIdx.x;  // grid = 2*8*nt = Tseg
  const int dir = wg / (8 * nt);
  const int rem = wg - dir * 8 * nt;
  const int chunk = rem / nt;
  const int tb = rem - chunk * nt;
  const int tid = threadIdx.x;
  const int wave = tid >> 6, lane = tid & 63;
  const int n16 = lane & 15, quad = lane >> 4;

  const float* wih = dir ? w_ih_b : w_ih_f;
  const float* bih = dir ? b_ih_b : b_ih_f;
  const float* bhh = dir ? b_hh_b : b_hh_f;

  // B-frags: B[k=e][col = g*128 + wave*16 + n16] = W_ih[col][e]
  half8_t bf[4][4];
  float bias[4];
#pragma unroll
  for (int g = 0; g < 4; ++g) {
    const int col = g * HH + wave * 16 + n16;
    bias[g] = bih[col] + bhh[col];
#pragma unroll
    for (int kf = 0; kf < 4; ++kf) {
      const float* src = wih + col * EE + kf * 32 + quad * 8;
#pragma unroll
      for (int i = 0; i < 8; ++i) bf[g][kf][i] = (_Float16)src[i];
    }
  }

  const int l0 = tb * 16;
  half8_t af[4];
  {
    const int te = dir ? (TT - 1 - (s * Tseg + l0)) : (s * Tseg + l0);
#pragma unroll
    for (int kf = 0; kf < 4; ++kf)
      af[kf] = *(const half8_t*)(x + ((size_t)te * BB + chunk * 16 + n16) * EE + kf * 32 + quad * 8);
  }
  for (int u = 0; u < 16; ++u) {
    const int l = l0 + u;
    half8_t afn[4] = {};
    if (u < 15) {
      const int tn = dir ? (TT - 1 - (s * Tseg + l + 1)) : (s * Tseg + l + 1);
#pragma unroll
      for (int kf = 0; kf < 4; ++kf)
        afn[kf] = *(const half8_t*)(x + ((size_t)tn * BB + chunk * 16 + n16) * EE + kf * 32 + quad * 8);
    }
    float4_t acc[4];
#pragma unroll
    for (int g = 0; g < 4; ++g) acc[g] = (float4_t){bias[g], bias[g], bias[g], bias[g]};
#pragma unroll
    for (int kf = 0; kf < 4; ++kf)
#pragma unroll
      for (int g = 0; g < 4; ++g)
        acc[g] = __builtin_amdgcn_mfma_f32_16x16x32_f16(af[kf], bf[g][kf], acc[g], 0, 0, 0);
    _Float16* ob = xgbuf + (size_t)dir * Tseg * 65536 + (size_t)l * 65536 + chunk * 8192 +
                   wave * 1024 + lane * 16;
#pragma unroll
    for (int g = 0; g < 4; ++g) {
      half4_t o;
#pragma unroll
      for (int r = 0; r < 4; ++r) o[r] = (_Float16)acc[g][r];
      *(half4_t*)(ob + g * 4) = o;  // 4 contiguous half4 -> compiler merges to 2x b128
    }
#pragma unroll
    for (int kf = 0; kf < 4; ++kf) af[kf] = afn[kf];
  }
}

// ---------------------------------------------------------------- bidirectional LSTM segment
// R6 orientation (C rows=batch, cols=hu), unroll-2, lane-major xg (2x b128/step),
// 6-instr packed-f16 activations, strength-reduced h_cat pointer.
__global__ __launch_bounds__(512, 2) void lstm_kernel(
    const _Float16* __restrict__ xgbuf,
    const float* __restrict__ w_hh_f, const float* __restrict__ w_hh_b,
    _Float16* __restrict__ h_cat, _Float16* __restrict__ h_state, float* __restrict__ c_state,
    int s, int Tseg) {
  __shared__ _Float16 A[2][16 * ASTR];
  const int wg = blockIdx.x;
  const int dir = wg >> 3, chunk = wg & 7;
  const int b0 = chunk * 16;
  const float* w_hh = dir ? w_hh_b : w_hh_f;
  const int tid = threadIdx.x;
  const int wave = tid >> 6, lane = tid & 63;
  const int n16 = lane & 15, quad = lane >> 4;
  const int hu = wave * 16 + n16;

  half8_t bf[4][4];  // B-frags of W_hh: B[k=h][col = g*128 + hu]
#pragma unroll
  for (int g = 0; g < 4; ++g) {
    const int ng = g * HH + hu;
#pragma unroll
    for (int kf = 0; kf < 4; ++kf) {
      const float* src = w_hh + ng * HH + kf * 32 + quad * 8;
#pragma unroll
      for (int i = 0; i < 8; ++i) bf[g][kf][i] = (_Float16)src[i];
    }
  }
  const int sidx = ((wg * 8 + wave) * 64 + lane) * 4;
  half4_t h4 = *(const half4_t*)(h_state + sidx);
  float4_t c4 = *(const float4_t*)(c_state + sidx);
  half2_t c2[2];
  c2[0] = cvt_pk(c4[0], c4[1]);
  c2[1] = cvt_pk(c4[2], c4[3]);
#pragma unroll
  for (int r = 0; r < 4; ++r) A[0][(quad * 4 + r) * ASTR + hu] = h4[r];

  const _Float16* xgw =
      xgbuf + (size_t)dir * Tseg * 65536 + chunk * 8192 + wave * 1024 + (size_t)lane * 16;
  half8_t xv0 = *(const half8_t*)xgw;
  half8_t xv1 = *(const half8_t*)(xgw + 8);
  half4_t hlast = h4;
  const int te0 = dir ? (TT - 1 - s * Tseg) : (s * Tseg);
  _Float16* gp_run = h_cat + ((size_t)te0 * BB + b0 + quad * 4) * 256 + dir * HH + hu;
  const ptrdiff_t dstep = dir ? -(ptrdiff_t)32768 : (ptrdiff_t)32768;
  lds_barrier();

#define LSTM_STEP(AB, AN, X0, X1)                                                          \
  {                                                                                        \
    const _Float16* Abp = &AB[0];                                                          \
    _Float16* Anp = &AN[0];                                                                \
    half8_t af0 = *(const half8_t*)(Abp + n16 * ASTR + 0 * 32 + quad * 8);                 \
    half8_t af1 = *(const half8_t*)(Abp + n16 * ASTR + 1 * 32 + quad * 8);                 \
    half8_t af2 = *(const half8_t*)(Abp + n16 * ASTR + 2 * 32 + quad * 8);                 \
    half8_t af3 = *(const half8_t*)(Abp + n16 * ASTR + 3 * 32 + quad * 8);                 \
    float4_t acc[4];                                                                       \
    acc[0] = (float4_t){(float)X0[0], (float)X0[1], (float)X0[2], (float)X0[3]};           \
    acc[1] = (float4_t){(float)X0[4], (float)X0[5], (float)X0[6], (float)X0[7]};           \
    acc[2] = (float4_t){(float)X1[0], (float)X1[1], (float)X1[2], (float)X1[3]};           \
    acc[3] = (float4_t){(float)X1[4], (float)X1[5], (float)X1[6], (float)X1[7]};           \
    _Pragma("unroll") for (int g = 0; g < 4; ++g) {                                        \
      acc[g] = __builtin_amdgcn_mfma_f32_16x16x32_f16(af0, bf[g][0], acc[g], 0, 0, 0);     \
    }                                                                                      \
    _Pragma("unroll") for (int g = 0; g < 4; ++g) {                                        \
      acc[g] = __builtin_amdgcn_mfma_f32_16x16x32_f16(af1, bf[g][1], acc[g], 0, 0, 0);     \
    }                                                                                      \
    _Pragma("unroll") for (int g = 0; g < 4; ++g) {                                        \
      acc[g] = __builtin_amdgcn_mfma_f32_16x16x32_f16(af2, bf[g][2], acc[g], 0, 0, 0);     \
    }                                                                                      \
    _Pragma("unroll") for (int g = 0; g < 4; ++g) {                                        \
      acc[g] = __builtin_amdgcn_mfma_f32_16x16x32_f16(af3, bf[g][3], acc[g], 0, 0, 0);     \
    }                                                                                      \
    _Pragma("unroll") for (int p = 0; p < 2; ++p) {                                        \
      const half2_t i_ = sig6(cvt_pk(acc[0][2 * p], acc[0][2 * p + 1]));                   \
      const half2_t f_ = sig6(cvt_pk(acc[1][2 * p], acc[1][2 * p + 1]));                   \
      const half2_t g_ = tanh6(cvt_pk(acc[2][2 * p], acc[2][2 * p + 1]));                  \
      const half2_t o_ = sig6(cvt_pk(acc[3][2 * p], acc[3][2 * p + 1]));                   \
      c2[p] = f_ * c2[p] + i_ * g_;                                                        \
      const half2_t hh = o_ * tanh6(c2[p]);                                                \
      Anp[(quad * 4 + 2 * p) * ASTR + hu] = hh[0];                                         \
      Anp[(quad * 4 + 2 * p + 1) * ASTR + hu] = hh[1];                                     \
      gp_run[(2 * p) * 256] = hh[0];                                                       \
      gp_run[(2 * p + 1) * 256] = hh[1];                                                   \
      hlast[2 * p] = hh[0];                                                                \
      hlast[2 * p + 1] = hh[1];                                                            \
    }                                                                                      \
  }

  for (int il = 0; il < Tseg; il += 2) {
    // substep 0 (even il): A[0] -> A[1]
    half8_t yn0, yn1;
    {
      const _Float16* p = xgw + (size_t)(il + 1) * 65536;
      yn0 = *(const half8_t*)p;
      yn1 = *(const half8_t*)(p + 8);
    }
    lds_barrier();
    LSTM_STEP(A[0], A[1], xv0, xv1);
    gp_run += dstep;
    // substep 1 (odd il): A[1] -> A[0]
    if (il + 2 < Tseg) {
      const _Float16* p = xgw + (size_t)(il + 2) * 65536;
      xv0 = *(const half8_t*)p;
      xv1 = *(const half8_t*)(p + 8);
    }
    lds_barrier();
    LSTM_STEP(A[1], A[0], yn0, yn1);
    gp_run += dstep;
  }
#undef LSTM_STEP

  *(half4_t*)(h_state + sidx) = hlast;
  c4[0] = (float)c2[0][0]; c4[1] = (float)c2[0][1];
  c4[2] = (float)c2[1][0]; c4[3] = (float)c2[1][1];
  *(float4_t*)(c_state + sidx) = c4;
}

// ---------------------------------------------------------------- emissions: em f32 + expem f16
__global__ __launch_bounds__(256) void emis_kernel(const _Float16* __restrict__ h_cat,
                                                   const float* __restrict__ w_proj,
                                                   const float* __restrict__ b_proj,
                                                   float* __restrict__ em,
                                                   _Float16* __restrict__ expem) {
  const int tid = threadIdx.x;
  const int wave = tid >> 6, lane = tid & 63;
  const int n16 = lane & 15, quad = lane >> 4;
  const size_t row0 = (size_t)blockIdx.x * 64 + wave * 16;

  half8_t bf[4][8];
#pragma unroll
  for (int nt = 0; nt < 4; ++nt) {
    const float* wp = w_proj + (nt * 16 + n16) * 256;
#pragma unroll
    for (int kf = 0; kf < 8; ++kf) {
      const int kb = kf * 32 + quad * 8;
#pragma unroll
      for (int i = 0; i < 8; ++i) bf[nt][kf][i] = (_Float16)wp[kb + i];
    }
  }
  float4_t acc[4];
#pragma unroll
  for (int nt = 0; nt < 4; ++nt) {
    const float bv = b_proj[nt * 16 + n16];
    acc[nt] = (float4_t){bv, bv, bv, bv};
  }
#pragma unroll
  for (int kf = 0; kf < 8; ++kf) {
    half8_t af = *(const half8_t*)(h_cat + (row0 + n16) * 256 + kf * 32 + quad * 8);
#pragma unroll
    for (int nt = 0; nt < 4; ++nt)
      acc[nt] = __builtin_amdgcn_mfma_f32_16x16x32_f16(af, bf[nt][kf], acc[nt], 0, 0, 0);
  }
#pragma unroll
  for (int nt = 0; nt < 4; ++nt)
#pragma unroll
    for (int r = 0; r < 4; ++r) {
      const size_t idx = (row0 + quad * 4 + r) * NTAG + nt * 16 + n16;
      em[idx] = acc[nt][r];
      expem[idx] = (_Float16)fast_exp(acc[nt][r]);
    }
}

// ---------------------------------------------------------------- CRF forward, scaled linear space
// alpha' = (alpha @ (exp(trans)/64)) * expem; renorm every 16 steps; 1-step prefetch (R7 form).
__global__ __launch_bounds__(64) void crf_kernel(const float* __restrict__ em,
                                                 const _Float16* __restrict__ expem,
                                                 const float* __restrict__ trans,
                                                 const float* __restrict__ start_trans,
                                                 const float* __restrict__ end_trans,
                                                 float* __restrict__ denom) {
  __shared__ float tmp[4 * 68 + 4];
  const int lane = threadIdx.x;
  const int n16 = lane & 15, quad = lane >> 4;
  const int b = n16 & 3;
  const int gb = blockIdx.x * 4 + b;

  half8_t ef[4][2];  // exp(trans)*2^-6 in B-frag layout [nt][kf]
#pragma unroll
  for (int nt = 0; nt < 4; ++nt)
#pragma unroll
    for (int kf = 0; kf < 2; ++kf)
#pragma unroll
      for (int i = 0; i < 8; ++i)
        ef[nt][kf][i] =
            (_Float16)(fast_exp(trans[(kf * 32 + quad * 8 + i) * NTAG + nt * 16 + n16]) * 0.015625f);

  float sv[16], et[16];
#pragma unroll
  for (int kf = 0; kf < 2; ++kf) {
    const int j0 = kf * 32 + quad * 8;
    float4_t s0 = *(const float4_t*)(start_trans + j0);
    float4_t s1 = *(const float4_t*)(start_trans + j0 + 4);
    float4_t e0 = *(const float4_t*)(end_trans + j0);
    float4_t e1 = *(const float4_t*)(end_trans + j0 + 4);
    float4_t m0v = *(const float4_t*)(em + (size_t)gb * NTAG + j0);
    float4_t m1v = *(const float4_t*)(em + (size_t)gb * NTAG + j0 + 4);
#pragma unroll
    for (int i = 0; i < 4; ++i) {
      sv[kf * 8 + i] = s0[i] + m0v[i];
      sv[kf * 8 + 4 + i] = s1[i] + m1v[i];
      et[kf * 8 + i] = e0[i];
      et[kf * 8 + 4 + i] = e1[i];
    }
  }
  float m0;
  {
    float mx[8];
#pragma unroll
    for (int i = 0; i < 8; ++i) mx[i] = fmaxf(sv[i], sv[8 + i]);
#pragma unroll
    for (int i = 0; i < 4; ++i) mx[i] = fmaxf(mx[i], mx[4 + i]);
    m0 = fmaxf(fmaxf(mx[0], mx[1]), fmaxf(mx[2], mx[3]));
    m0 = fmaxf(m0, __shfl_xor(m0, 16, 64));
    m0 = fmaxf(m0, __shfl_xor(m0, 32, 64));
  }
  half8_t pa[2];
#pragma unroll
  for (int kf = 0; kf < 2; ++kf)
#pragma unroll
    for (int i = 0; i < 8; ++i) pa[kf][i] = (_Float16)fast_exp(sv[kf * 8 + i] - m0);
  float lz2 = 0.f;
  const float4_t z4 = {0.f, 0.f, 0.f, 0.f};

  const _Float16* exb = expem + (size_t)gb * NTAG;
  half8_t gn0 = *(const half8_t*)(exb + 8192 + quad * 8);
  half8_t gn1 = *(const half8_t*)(exb + 8192 + 32 + quad * 8);

  for (int t = 1; t < TT; ++t) {
    const half8_t gc0 = gn0, gc1 = gn1;
    if (t + 1 < TT) {
      gn0 = *(const half8_t*)(exb + (size_t)(t + 1) * 8192 + quad * 8);
      gn1 = *(const half8_t*)(exb + (size_t)(t + 1) * 8192 + 32 + quad * 8);
    }
    float4_t u0 = __builtin_amdgcn_mfma_f32_16x16x32_f16(pa[0], ef[0][0], z4, 0, 0, 0);
    float4_t u1 = __builtin_amdgcn_mfma_f32_16x16x32_f16(pa[0], ef[1][0], z4, 0, 0, 0);
    float4_t u2 = __builtin_amdgcn_mfma_f32_16x16x32_f16(pa[0], ef[2][0], z4, 0, 0, 0);
    float4_t u3 = __builtin_amdgcn_mfma_f32_16x16x32_f16(pa[0], ef[3][0], z4, 0, 0, 0);
    float4_t w0 = __builtin_amdgcn_mfma_f32_16x16x32_f16(pa[1], ef[0][1], z4, 0, 0, 0);
    float4_t w1 = __builtin_amdgcn_mfma_f32_16x16x32_f16(pa[1], ef[1][1], z4, 0, 0, 0);
    float4_t w2 = __builtin_amdgcn_mfma_f32_16x16x32_f16(pa[1], ef[2][1], z4, 0, 0, 0);
    float4_t w3 = __builtin_amdgcn_mfma_f32_16x16x32_f16(pa[1], ef[3][1], z4, 0, 0, 0);
    const float4_t a0 = u0 + w0, a1 = u1 + w1, a2 = u2 + w2, a3 = u3 + w3;
    const float4_t aq = (quad == 0) ? a0 : (quad == 1) ? a1 : (quad == 2) ? a2 : a3;
    tmp[0 * 68 + quad * 16 + n16] = aq[0];
    tmp[1 * 68 + quad * 16 + n16] = aq[1];
    tmp[2 * 68 + quad * 16 + n16] = aq[2];
    tmp[3 * 68 + quad * 16 + n16] = aq[3];
    lds_fence();
    const float4_t v0 = *(const float4_t*)(&tmp[b * 68 + quad * 8]);
    const float4_t v1 = *(const float4_t*)(&tmp[b * 68 + quad * 8 + 4]);
    const float4_t v2 = *(const float4_t*)(&tmp[b * 68 + 32 + quad * 8]);
    const float4_t v3 = *(const float4_t*)(&tmp[b * 68 + 32 + quad * 8 + 4]);
    half2_t* p0 = (half2_t*)&pa[0];
    half2_t* p1 = (half2_t*)&pa[1];
    const half2_t* g0 = (const half2_t*)&gc0;
    const half2_t* g1 = (const half2_t*)&gc1;
    p0[0] = cvt_pk(v0[0], v0[1]) * g0[0];
    p0[1] = cvt_pk(v0[2], v0[3]) * g0[1];
    p0[2] = cvt_pk(v1[0], v1[1]) * g0[2];
    p0[3] = cvt_pk(v1[2], v1[3]) * g0[3];
    p1[0] = cvt_pk(v2[0], v2[1]) * g1[0];
    p1[1] = cvt_pk(v2[2], v2[3]) * g1[1];
    p1[2] = cvt_pk(v3[0], v3[1]) * g1[2];
    p1[3] = cvt_pk(v3[2], v3[3]) * g1[3];
    if ((t & 15) == 0) {
      half2_t m2 = __builtin_elementwise_max(p0[0], p0[1]);
      m2 = __builtin_elementwise_max(m2, __builtin_elementwise_max(p0[2], p0[3]));
      m2 = __builtin_elementwise_max(m2, __builtin_elementwise_max(p1[0], p1[1]));
      m2 = __builtin_elementwise_max(m2, __builtin_elementwise_max(p1[2], p1[3]));
      float mm = fmaxf((float)m2[0], (float)m2[1]);
      mm = fmaxf(mm, __shfl_xor(mm, 16, 64));
      mm = fmaxf(mm, __shfl_xor(mm, 32, 64));
      lz2 += __builtin_amdgcn_logf(mm);  // log2
      const half2_t rc = h2bc(__builtin_amdgcn_rcpf(mm));
#pragma unroll
      for (int j = 0; j < 4; ++j) { p0[j] *= rc; p1[j] *= rc; }
    }
  }

  float w = 0.f;
#pragma unroll
  for (int kf = 0; kf < 2; ++kf)
#pragma unroll
    for (int i = 0; i < 8; ++i) w += (float)pa[kf][i] * fast_exp(et[kf * 8 + i]);
  w += __shfl_xor(w, 16, 64);
  w += __shfl_xor(w, 32, 64);
  if (lane < 4)
    denom[blockIdx.x * 4 + lane] =
        m0 + 0.693147180559945f * (lz2 + 6138.0f + __builtin_amdgcn_logf(w));
}

// ---------------------------------------------------------------- numerator
__global__ __launch_bounds__(256) void numer_kernel(const float* __restrict__ em,
                                                    const int* __restrict__ tags,
                                                    const float* __restrict__ trans,
                                                    const float* __restrict__ start_trans,
                                                    const float* __restrict__ end_trans,
                                                    float* __restrict__ num) {
  const int b = blockIdx.x;
  const int tg = tags[b];
  float acc = 0.f;
  for (int t = threadIdx.x; t < TT; t += 256)
    acc += em[((size_t)t * BB + b) * NTAG + tg];
#pragma unroll
  for (int off = 32; off > 0; off >>= 1) acc += __shfl_xor(acc, off, 64);
  __shared__ float red[4];
  if ((threadIdx.x & 63) == 0) red[threadIdx.x >> 6] = acc;
  __syncthreads();
  if (threadIdx.x == 0) {
    const float tot = red[0] + red[1] + red[2] + red[3];
    num[b] = start_trans[tg] + end_trans[tg] + 1023.0f * trans[tg * NTAG + tg] + tot;
  }
}

// ---------------------------------------------------------------- final
__global__ __launch_bounds__(128) void final_kernel(const float* __restrict__ denom,
                                                    const float* __restrict__ num,
                                                    float* __restrict__ out) {
  const int tid = threadIdx.x;
  float v = denom[tid] - num[tid];
#pragma unroll
  for (int off = 32; off > 0; off >>= 1) v += __shfl_xor(v, off, 64);
  __shared__ float red[2];
  if ((tid & 63) == 0) red[tid >> 6] = v;
  __syncthreads();
  if (tid == 0) out[0] = red[0] + red[1];
}

extern "C" void kernel_launch(void* const* d_in, const int* in_sizes, int n_in,
                              void* d_out, int out_size, void* d_ws, size_t ws_size,
                              hipStream_t stream) {
  const int* kmers = (const int*)d_in[0];
  const int* tags = (const int*)d_in[1];
  const float* emb = (const float*)d_in[2];
  const float* w_ih_f = (const float*)d_in[3];
  const float* w_hh_f = (const float*)d_in[4];
  const float* b_ih_f = (const float*)d_in[5];
  const float* b_hh_f = (const float*)d_in[6];
  const float* w_ih_b = (const float*)d_in[7];
  const float* w_hh_b = (const float*)d_in[8];
  const float* b_ih_b = (const float*)d_in[9];
  const float* b_hh_b = (const float*)d_in[10];
  const float* w_proj = (const float*)d_in[11];
  const float* b_proj = (const float*)d_in[12];
  const float* start_trans = (const float*)d_in[13];
  const float* end_trans = (const float*)d_in[14];
  const float* trans = (const float*)d_in[15];

  int nseg;
  if (ws_size >= 235078656ull) nseg = 2;
  else if (ws_size >= 167969792ull) nseg = 4;
  else if (ws_size >= 134415360ull) nseg = 8;
  else nseg = 16;
  const int Tseg = TT / nseg;
  const size_t xg_bytes = 268435456ull / (size_t)nseg;

  char* ws = (char*)d_ws;
  half4_t* x = (half4_t*)ws;                       // [0, 33.5M); em aliases after xg done
  _Float16* h_cat = (_Float16*)(ws + 33554432);    // [33.5M, 100.7M)
  _Float16* xgbuf = (_Float16*)(ws + 100663296);   // [100.7M, +xg_bytes)
  _Float16* expem = (_Float16*)(ws + 100663296);   // 16.8M, aliases xgbuf (dead after lstm)
  _Float16* h_state = (_Float16*)(ws + 100663296 + xg_bytes);    // 65,536 B
  float* c_state = (float*)(ws + 100663296 + xg_bytes + 65536);  // 131,072 B
  float* denom = (float*)(ws + 100663296 + xg_bytes + 196608);   // 512 B
  float* num = denom + 128;
  float* em = (float*)ws;
  float* out = (float*)d_out;

  hipLaunchKernelGGL(init_kernel, dim3(48), dim3(256), 0, stream, (float4_t*)h_state);
  hipLaunchKernelGGL(embed_kernel, dim3(16384), dim3(256), 0, stream, kmers, emb, x);
  for (int s = 0; s < nseg; ++s) {
    hipLaunchKernelGGL(xg_kernel, dim3(Tseg), dim3(512), 0, stream, (const _Float16*)x,
                       w_ih_f, b_ih_f, b_hh_f, w_ih_b, b_ih_b, b_hh_b, xgbuf, s, Tseg);
    hipLaunchKernelGGL(lstm_kernel, dim3(16), dim3(512), 0, stream, (const _Float16*)xgbuf,
                       w_hh_f, w_hh_b, h_cat, h_state, c_state, s, Tseg);
  }
  hipLaunchKernelGGL(emis_kernel, dim3(2048), dim3(256), 0, stream, h_cat, w_proj, b_proj, em,
                     expem);
  hipLaunchKernelGGL(crf_kernel, dim3(32), dim3(64), 0, stream, em, (const _Float16*)expem,
                     trans, start_trans, end_trans, denom);
  hipLaunchKernelGGL(numer_kernel, dim3(128), dim3(256), 0, stream, em, tags, trans, start_trans,
                     end_trans, num);
  hipLaunchKernelGGL(final_kernel, dim3(1), dim3(128), 0, stream, denom, num, out);
}

// Round 10
// 1293.959 us; speedup vs baseline: 1.1733x; 1.1248x over previous
//
#include <hip/hip_runtime.h>
#include <hip/hip_bf16.h>

typedef _Float16 half8_t __attribute__((ext_vector_type(8)));
typedef _Float16 half4_t __attribute__((ext_vector_type(4)));
typedef _Float16 half2_t __attribute__((ext_vector_type(2)));
typedef float float4_t __attribute__((ext_vector_type(4)));

#define TT 1024
#define BB 128
#define EE 128
#define HH 128
#define NTAG 64
#define ASTR 144  // [batch][hu] LDS panel stride (f16) — R6-proven for the b128 read pattern

__device__ __forceinline__ float fast_exp(float x) {
  return __builtin_amdgcn_exp2f(x * 1.44269504088896f);
}
// LDS-only barrier: does NOT drain vmcnt -> global loads/stores stay in flight.
__device__ __forceinline__ void lds_barrier() {
  asm volatile("s_waitcnt lgkmcnt(0)\n\ts_barrier" ::: "memory");
}
// Single-wave LDS write->read fence.
__device__ __forceinline__ void lds_fence() {
  asm volatile("s_waitcnt lgkmcnt(0)" ::: "memory");
}
__device__ __forceinline__ half2_t cvt_pk(float a, float b) {
  return __builtin_bit_cast(half2_t, __builtin_amdgcn_cvt_pkrtz(a, b));
}
__device__ __forceinline__ half2_t h2bc(float v) {
  _Float16 h = (_Float16)v;
  half2_t r; r[0] = h; r[1] = h;
  return r;
}
// deg-5 odd tanh poly (fit at 1, 1.6; clamp +-1.6): 6 pk instrs
__device__ __forceinline__ half2_t tanh6(half2_t x) {
  half2_t y = __builtin_elementwise_min(__builtin_elementwise_max(x, h2bc(-1.6f)), h2bc(1.6f));
  half2_t u = y * y;
  half2_t p = u * h2bc(0.04667f) + h2bc(-0.28507f);
  p = u * p + h2bc(1.0f);
  return y * p;
}
// sigmoid, x/2 folded into coefficients: 6 pk instrs
__device__ __forceinline__ half2_t sig6(half2_t x) {
  half2_t y = __builtin_elementwise_min(__builtin_elementwise_max(x, h2bc(-3.2f)), h2bc(3.2f));
  half2_t u = y * y;
  half2_t q = u * h2bc(0.00072921875f) + h2bc(-0.017816875f);
  q = u * q + h2bc(0.25f);
  return y * q + h2bc(0.5f);
}

// ---------------------------------------------------------------- init: zero LSTM state
__global__ __launch_bounds__(256) void init_kernel(float4_t* __restrict__ p) {
  p[blockIdx.x * 256 + threadIdx.x] = (float4_t){0.f, 0.f, 0.f, 0.f};
}

// ---------------------------------------------------------------- embed: x[t*B+b][e] f16
__global__ __launch_bounds__(256) void embed_kernel(const int* __restrict__ kmers,
                                                    const float* __restrict__ emb,
                                                    half4_t* __restrict__ x) {
  const int g = blockIdx.x * 256 + threadIdx.x;
  const int row = g >> 5, seg = g & 31;
  const int km = kmers[row];
  const float4_t v = ((const float4_t*)(emb + (size_t)km * EE))[seg];
  half4_t o;
  o[0] = (_Float16)v[0]; o[1] = (_Float16)v[1];
  o[2] = (_Float16)v[2]; o[3] = (_Float16)v[3];
  x[(size_t)row * 32 + seg] = o;
}

// ---------------------------------------------------------------- xg segment
// Orientation: A = W_ih (regs), B = x^T (b128 global loads), C rows=hu-part, col=batch.
// Lane output = 16 contiguous f16 (4 gates x 4 hu at one batch): 2x b128 stores.
// Layout: dir*Tseg*65536 + l*65536 + chunk*8192 + wave*1024 + lane*16 + g*4 + r
__global__ __launch_bounds__(512) void xg_kernel(
    const _Float16* __restrict__ x,
    const float* __restrict__ w_ih_f, const float* __restrict__ b_ih_f, const float* __restrict__ b_hh_f,
    const float* __restrict__ w_ih_b, const float* __restrict__ b_ih_b, const float* __restrict__ b_hh_b,
    _Float16* __restrict__ xgbuf, int s, int Tseg) {
  const int nt = Tseg >> 4;
  const int wg = blockIdx.x;  // grid = 2*8*nt = Tseg
  const int dir = wg / (8 * nt);
  const int rem = wg - dir * 8 * nt;
  const int chunk = rem / nt;
  const int tb = rem - chunk * nt;
  const int tid = threadIdx.x;
  const int wave = tid >> 6, lane = tid & 63;
  const int n16 = lane & 15, quad = lane >> 4;

  const float* wih = dir ? w_ih_b : w_ih_f;
  const float* bih = dir ? b_ih_b : b_ih_f;
  const float* bhh = dir ? b_hh_b : b_hh_f;

  // A-frags of W_ih: lane holds W[g*128 + wave*16 + n16][kf*32 + quad*8 + j]
  half8_t wf[4][4];
#pragma unroll
  for (int g = 0; g < 4; ++g) {
    const int row = g * HH + wave * 16 + n16;
#pragma unroll
    for (int kf = 0; kf < 4; ++kf) {
      const float* src = wih + row * EE + kf * 32 + quad * 8;
#pragma unroll
      for (int i = 0; i < 8; ++i) wf[g][kf][i] = (_Float16)src[i];
    }
  }
  // bias as C-init: rows m = quad*4+r -> hu = wave*16 + quad*4 + r
  float4_t bias4[4];
#pragma unroll
  for (int g = 0; g < 4; ++g) {
    const int row = g * HH + wave * 16 + quad * 4;
    const float4_t bi = *(const float4_t*)(bih + row);
    const float4_t bh = *(const float4_t*)(bhh + row);
    bias4[g] = bi + bh;
  }

  const int l0 = tb * 16;
  half8_t xb[4];
  {
    const int te = dir ? (TT - 1 - (s * Tseg + l0)) : (s * Tseg + l0);
#pragma unroll
    for (int kf = 0; kf < 4; ++kf)
      xb[kf] = *(const half8_t*)(x + ((size_t)te * BB + chunk * 16 + n16) * EE + kf * 32 + quad * 8);
  }
  for (int u = 0; u < 16; ++u) {
    const int l = l0 + u;
    half8_t xn[4] = {};
    if (u < 15) {
      const int tn = dir ? (TT - 1 - (s * Tseg + l + 1)) : (s * Tseg + l + 1);
#pragma unroll
      for (int kf = 0; kf < 4; ++kf)
        xn[kf] = *(const half8_t*)(x + ((size_t)tn * BB + chunk * 16 + n16) * EE + kf * 32 + quad * 8);
    }
    float4_t acc[4];
#pragma unroll
    for (int g = 0; g < 4; ++g) acc[g] = bias4[g];
#pragma unroll
    for (int kf = 0; kf < 4; ++kf)
#pragma unroll
      for (int g = 0; g < 4; ++g)
        acc[g] = __builtin_amdgcn_mfma_f32_16x16x32_f16(wf[g][kf], xb[kf], acc[g], 0, 0, 0);
    half8_t ho0, ho1;
#pragma unroll
    for (int r = 0; r < 4; ++r) {
      ho0[r] = (_Float16)acc[0][r];
      ho0[4 + r] = (_Float16)acc[1][r];
      ho1[r] = (_Float16)acc[2][r];
      ho1[4 + r] = (_Float16)acc[3][r];
    }
    _Float16* ob = xgbuf + (size_t)dir * Tseg * 65536 + (size_t)l * 65536 + chunk * 8192 +
                   wave * 1024 + lane * 16;
    *(half8_t*)ob = ho0;
    *(half8_t*)(ob + 8) = ho1;
#pragma unroll
    for (int kf = 0; kf < 4; ++kf) xb[kf] = xn[kf];
  }
}

// ---------------------------------------------------------------- bidirectional LSTM segment
// A = W_hh (regs), B = h^T (LDS [batch][hu], b128 reads), C rows=hu, col=batch.
// Lane epilogue: 4 contiguous hu at one batch -> 1 b64 LDS write + 1 b64 global store.
__global__ __launch_bounds__(512, 2) void lstm_kernel(
    const _Float16* __restrict__ xgbuf,
    const float* __restrict__ w_hh_f, const float* __restrict__ w_hh_b,
    _Float16* __restrict__ h_cat, _Float16* __restrict__ h_state, float* __restrict__ c_state,
    int s, int Tseg) {
  __shared__ _Float16 A[2][16 * ASTR];
  const int wg = blockIdx.x;
  const int dir = wg >> 3, chunk = wg & 7;
  const int b0 = chunk * 16;
  const float* w_hh = dir ? w_hh_b : w_hh_f;
  const int tid = threadIdx.x;
  const int wave = tid >> 6, lane = tid & 63;
  const int n16 = lane & 15, quad = lane >> 4;

  // A-frags of W_hh
  half8_t wf[4][4];
#pragma unroll
  for (int g = 0; g < 4; ++g) {
    const int row = g * HH + wave * 16 + n16;
#pragma unroll
    for (int kf = 0; kf < 4; ++kf) {
      const float* src = w_hh + row * HH + kf * 32 + quad * 8;
#pragma unroll
      for (int i = 0; i < 8; ++i) wf[g][kf][i] = (_Float16)src[i];
    }
  }
  // persistent state: lane holds h/c for hu = wave*16+quad*4+r, batch = b0+n16
  const int sidx = ((wg * 8 + wave) * 64 + lane) * 4;
  half4_t h4 = *(const half4_t*)(h_state + sidx);
  float4_t c4 = *(const float4_t*)(c_state + sidx);
  half2_t c2[2];
  c2[0] = cvt_pk(c4[0], c4[1]);
  c2[1] = cvt_pk(c4[2], c4[3]);
  *(half4_t*)(&A[0][n16 * ASTR + wave * 16 + quad * 4]) = h4;  // seed h_{-1}

  const _Float16* xgw =
      xgbuf + (size_t)dir * Tseg * 65536 + chunk * 8192 + wave * 1024 + (size_t)lane * 16;
  half8_t xv0 = *(const half8_t*)xgw;
  half8_t xv1 = *(const half8_t*)(xgw + 8);
  half4_t hlast = h4;
  const float4_t z4 = {0.f, 0.f, 0.f, 0.f};  // persistent zero C-init
  const int te0 = dir ? (TT - 1 - s * Tseg) : (s * Tseg);
  _Float16* gp_run =
      h_cat + ((size_t)te0 * BB + b0 + n16) * 256 + dir * HH + wave * 16 + quad * 4;
  const ptrdiff_t dstep = dir ? -(ptrdiff_t)32768 : (ptrdiff_t)32768;
  lds_barrier();

#define LSTM_STEP(AB, AN, X0, X1)                                                          \
  {                                                                                        \
    const _Float16* Abp = &AB[0];                                                          \
    _Float16* Anp = &AN[0];                                                                \
    half8_t hb0 = *(const half8_t*)(Abp + n16 * ASTR + 0 * 32 + quad * 8);                 \
    half8_t hb1 = *(const half8_t*)(Abp + n16 * ASTR + 1 * 32 + quad * 8);                 \
    half8_t hb2 = *(const half8_t*)(Abp + n16 * ASTR + 2 * 32 + quad * 8);                 \
    half8_t hb3 = *(const half8_t*)(Abp + n16 * ASTR + 3 * 32 + quad * 8);                 \
    float4_t acc[4];                                                                       \
    _Pragma("unroll") for (int g = 0; g < 4; ++g) {                                        \
      acc[g] = __builtin_amdgcn_mfma_f32_16x16x32_f16(wf[g][0], hb0, z4, 0, 0, 0);         \
    }                                                                                      \
    _Pragma("unroll") for (int g = 0; g < 4; ++g) {                                        \
      acc[g] = __builtin_amdgcn_mfma_f32_16x16x32_f16(wf[g][1], hb1, acc[g], 0, 0, 0);     \
    }                                                                                      \
    _Pragma("unroll") for (int g = 0; g < 4; ++g) {                                        \
      acc[g] = __builtin_amdgcn_mfma_f32_16x16x32_f16(wf[g][2], hb2, acc[g], 0, 0, 0);     \
    }                                                                                      \
    _Pragma("unroll") for (int g = 0; g < 4; ++g) {                                        \
      acc[g] = __builtin_amdgcn_mfma_f32_16x16x32_f16(wf[g][3], hb3, acc[g], 0, 0, 0);     \
    }                                                                                      \
    const half2_t* x0p = (const half2_t*)&X0;                                              \
    const half2_t* x1p = (const half2_t*)&X1;                                              \
    half4_t hstore;                                                                        \
    _Pragma("unroll") for (int p = 0; p < 2; ++p) {                                        \
      const half2_t i_ = sig6(cvt_pk(acc[0][2 * p], acc[0][2 * p + 1]) + x0p[p]);          \
      const half2_t f_ = sig6(cvt_pk(acc[1][2 * p], acc[1][2 * p + 1]) + x0p[2 + p]);      \
      const half2_t g_ = tanh6(cvt_pk(acc[2][2 * p], acc[2][2 * p + 1]) + x1p[p]);         \
      const half2_t o_ = sig6(cvt_pk(acc[3][2 * p], acc[3][2 * p + 1]) + x1p[2 + p]);      \
      c2[p] = f_ * c2[p] + i_ * g_;                                                        \
      const half2_t hh = o_ * tanh6(c2[p]);                                                \
      hstore[2 * p] = hh[0];                                                               \
      hstore[2 * p + 1] = hh[1];                                                           \
    }                                                                                      \
    *(half4_t*)(Anp + n16 * ASTR + wave * 16 + quad * 4) = hstore;                         \
    *(half4_t*)gp_run = hstore;                                                            \
    hlast = hstore;                                                                        \
  }

  for (int il = 0; il < Tseg; il += 2) {
    // substep 0 (even il): A[0] -> A[1]
    half8_t yn0, yn1;
    {
      const _Float16* p = xgw + (size_t)(il + 1) * 65536;
      yn0 = *(const half8_t*)p;
      yn1 = *(const half8_t*)(p + 8);
    }
    lds_barrier();
    LSTM_STEP(A[0], A[1], xv0, xv1);
    gp_run += dstep;
    // substep 1 (odd il): A[1] -> A[0]
    if (il + 2 < Tseg) {
      const _Float16* p = xgw + (size_t)(il + 2) * 65536;
      xv0 = *(const half8_t*)p;
      xv1 = *(const half8_t*)(p + 8);
    }
    lds_barrier();
    LSTM_STEP(A[1], A[0], yn0, yn1);
    gp_run += dstep;
  }
#undef LSTM_STEP

  *(half4_t*)(h_state + sidx) = hlast;
  c4[0] = (float)c2[0][0]; c4[1] = (float)c2[0][1];
  c4[2] = (float)c2[1][0]; c4[3] = (float)c2[1][1];
  *(float4_t*)(c_state + sidx) = c4;
}

// ---------------------------------------------------------------- emissions: em f32 + expem f16
__global__ __launch_bounds__(256) void emis_kernel(const _Float16* __restrict__ h_cat,
                                                   const float* __restrict__ w_proj,
                                                   const float* __restrict__ b_proj,
                                                   float* __restrict__ em,
                                                   _Float16* __restrict__ expem) {
  const int tid = threadIdx.x;
  const int wave = tid >> 6, lane = tid & 63;
  const int n16 = lane & 15, quad = lane >> 4;
  const size_t row0 = (size_t)blockIdx.x * 64 + wave * 16;

  half8_t bf[4][8];
#pragma unroll
  for (int nt = 0; nt < 4; ++nt) {
    const float* wp = w_proj + (nt * 16 + n16) * 256;
#pragma unroll
    for (int kf = 0; kf < 8; ++kf) {
      const int kb = kf * 32 + quad * 8;
#pragma unroll
      for (int i = 0; i < 8; ++i) bf[nt][kf][i] = (_Float16)wp[kb + i];
    }
  }
  float4_t acc[4];
#pragma unroll
  for (int nt = 0; nt < 4; ++nt) {
    const float bv = b_proj[nt * 16 + n16];
    acc[nt] = (float4_t){bv, bv, bv, bv};
  }
#pragma unroll
  for (int kf = 0; kf < 8; ++kf) {
    half8_t af = *(const half8_t*)(h_cat + (row0 + n16) * 256 + kf * 32 + quad * 8);
#pragma unroll
    for (int nt = 0; nt < 4; ++nt)
      acc[nt] = __builtin_amdgcn_mfma_f32_16x16x32_f16(af, bf[nt][kf], acc[nt], 0, 0, 0);
  }
#pragma unroll
  for (int nt = 0; nt < 4; ++nt)
#pragma unroll
    for (int r = 0; r < 4; ++r) {
      const size_t idx = (row0 + quad * 4 + r) * NTAG + nt * 16 + n16;
      em[idx] = acc[nt][r];
      expem[idx] = (_Float16)fast_exp(acc[nt][r]);
    }
}

// ---------------------------------------------------------------- CRF forward, scaled linear space
__global__ __launch_bounds__(64) void crf_kernel(const float* __restrict__ em,
                                                 const _Float16* __restrict__ expem,
                                                 const float* __restrict__ trans,
                                                 const float* __restrict__ start_trans,
                                                 const float* __restrict__ end_trans,
                                                 float* __restrict__ denom) {
  __shared__ float tmp[4 * 68 + 4];
  const int lane = threadIdx.x;
  const int n16 = lane & 15, quad = lane >> 4;
  const int b = n16 & 3;
  const int gb = blockIdx.x * 4 + b;

  half8_t ef[4][2];  // exp(trans)*2^-6 in B-frag layout [nt][kf]
#pragma unroll
  for (int nt = 0; nt < 4; ++nt)
#pragma unroll
    for (int kf = 0; kf < 2; ++kf)
#pragma unroll
      for (int i = 0; i < 8; ++i)
        ef[nt][kf][i] =
            (_Float16)(fast_exp(trans[(kf * 32 + quad * 8 + i) * NTAG + nt * 16 + n16]) * 0.015625f);

  float sv[16], et[16];
#pragma unroll
  for (int kf = 0; kf < 2; ++kf) {
    const int j0 = kf * 32 + quad * 8;
    float4_t s0 = *(const float4_t*)(start_trans + j0);
    float4_t s1 = *(const float4_t*)(start_trans + j0 + 4);
    float4_t e0 = *(const float4_t*)(end_trans + j0);
    float4_t e1 = *(const float4_t*)(end_trans + j0 + 4);
    float4_t m0v = *(const float4_t*)(em + (size_t)gb * NTAG + j0);
    float4_t m1v = *(const float4_t*)(em + (size_t)gb * NTAG + j0 + 4);
#pragma unroll
    for (int i = 0; i < 4; ++i) {
      sv[kf * 8 + i] = s0[i] + m0v[i];
      sv[kf * 8 + 4 + i] = s1[i] + m1v[i];
      et[kf * 8 + i] = e0[i];
      et[kf * 8 + 4 + i] = e1[i];
    }
  }
  float m0;
  {
    float mx[8];
#pragma unroll
    for (int i = 0; i < 8; ++i) mx[i] = fmaxf(sv[i], sv[8 + i]);
#pragma unroll
    for (int i = 0; i < 4; ++i) mx[i] = fmaxf(mx[i], mx[4 + i]);
    m0 = fmaxf(fmaxf(mx[0], mx[1]), fmaxf(mx[2], mx[3]));
    m0 = fmaxf(m0, __shfl_xor(m0, 16, 64));
    m0 = fmaxf(m0, __shfl_xor(m0, 32, 64));
  }
  half8_t pa[2];
#pragma unroll
  for (int kf = 0; kf < 2; ++kf)
#pragma unroll
    for (int i = 0; i < 8; ++i) pa[kf][i] = (_Float16)fast_exp(sv[kf * 8 + i] - m0);
  float lz2 = 0.f;
  const float4_t z4 = {0.f, 0.f, 0.f, 0.f};

  const _Float16* exb = expem + (size_t)gb * NTAG;
  half8_t gn0 = *(const half8_t*)(exb + 8192 + quad * 8);
  half8_t gn1 = *(const half8_t*)(exb + 8192 + 32 + quad * 8);

  for (int t = 1; t < TT; ++t) {
    const half8_t gc0 = gn0, gc1 = gn1;
    if (t + 1 < TT) {
      gn0 = *(const half8_t*)(exb + (size_t)(t + 1) * 8192 + quad * 8);
      gn1 = *(const half8_t*)(exb + (size_t)(t + 1) * 8192 + 32 + quad * 8);
    }
    float4_t u0 = __builtin_amdgcn_mfma_f32_16x16x32_f16(pa[0], ef[0][0], z4, 0, 0, 0);
    float4_t u1 = __builtin_amdgcn_mfma_f32_16x16x32_f16(pa[0], ef[1][0], z4, 0, 0, 0);
    float4_t u2 = __builtin_amdgcn_mfma_f32_16x16x32_f16(pa[0], ef[2][0], z4, 0, 0, 0);
    float4_t u3 = __builtin_amdgcn_mfma_f32_16x16x32_f16(pa[0], ef[3][0], z4, 0, 0, 0);
    float4_t w0 = __builtin_amdgcn_mfma_f32_16x16x32_f16(pa[1], ef[0][1], z4, 0, 0, 0);
    float4_t w1 = __builtin_amdgcn_mfma_f32_16x16x32_f16(pa[1], ef[1][1], z4, 0, 0, 0);
    float4_t w2 = __builtin_amdgcn_mfma_f32_16x16x32_f16(pa[1], ef[2][1], z4, 0, 0, 0);
    float4_t w3 = __builtin_amdgcn_mfma_f32_16x16x32_f16(pa[1], ef[3][1], z4, 0, 0, 0);
    const float4_t a0 = u0 + w0, a1 = u1 + w1, a2 = u2 + w2, a3 = u3 + w3;
    const float4_t aq = (quad == 0) ? a0 : (quad == 1) ? a1 : (quad == 2) ? a2 : a3;
    tmp[0 * 68 + quad * 16 + n16] = aq[0];
    tmp[1 * 68 + quad * 16 + n16] = aq[1];
    tmp[2 * 68 + quad * 16 + n16] = aq[2];
    tmp[3 * 68 + quad * 16 + n16] = aq[3];
    lds_fence();
    const float4_t v0 = *(const float4_t*)(&tmp[b * 68 + quad * 8]);
    const float4_t v1 = *(const float4_t*)(&tmp[b * 68 + quad * 8 + 4]);
    const float4_t v2 = *(const float4_t*)(&tmp[b * 68 + 32 + quad * 8]);
    const float4_t v3 = *(const float4_t*)(&tmp[b * 68 + 32 + quad * 8 + 4]);
    half2_t* p0 = (half2_t*)&pa[0];
    half2_t* p1 = (half2_t*)&pa[1];
    const half2_t* g0 = (const half2_t*)&gc0;
    const half2_t* g1 = (const half2_t*)&gc1;
    p0[0] = cvt_pk(v0[0], v0[1]) * g0[0];
    p0[1] = cvt_pk(v0[2], v0[3]) * g0[1];
    p0[2] = cvt_pk(v1[0], v1[1]) * g0[2];
    p0[3] = cvt_pk(v1[2], v1[3]) * g0[3];
    p1[0] = cvt_pk(v2[0], v2[1]) * g1[0];
    p1[1] = cvt_pk(v2[2], v2[3]) * g1[1];
    p1[2] = cvt_pk(v3[0], v3[1]) * g1[2];
    p1[3] = cvt_pk(v3[2], v3[3]) * g1[3];
    if ((t & 15) == 0) {
      half2_t m2 = __builtin_elementwise_max(p0[0], p0[1]);
      m2 = __builtin_elementwise_max(m2, __builtin_elementwise_max(p0[2], p0[3]));
      m2 = __builtin_elementwise_max(m2, __builtin_elementwise_max(p1[0], p1[1]));
      m2 = __builtin_elementwise_max(m2, __builtin_elementwise_max(p1[2], p1[3]));
      float mm = fmaxf((float)m2[0], (float)m2[1]);
      mm = fmaxf(mm, __shfl_xor(mm, 16, 64));
      mm = fmaxf(mm, __shfl_xor(mm, 32, 64));
      lz2 += __builtin_amdgcn_logf(mm);  // log2
      const half2_t rc = h2bc(__builtin_amdgcn_rcpf(mm));
#pragma unroll
      for (int j = 0; j < 4; ++j) { p0[j] *= rc; p1[j] *= rc; }
    }
  }

  float w = 0.f;
#pragma unroll
  for (int kf = 0; kf < 2; ++kf)
#pragma unroll
    for (int i = 0; i < 8; ++i) w += (float)pa[kf][i] * fast_exp(et[kf * 8 + i]);
  w += __shfl_xor(w, 16, 64);
  w += __shfl_xor(w, 32, 64);
  if (lane < 4)
    denom[blockIdx.x * 4 + lane] =
        m0 + 0.693147180559945f * (lz2 + 6138.0f + __builtin_amdgcn_logf(w));
}

// ---------------------------------------------------------------- numerator
__global__ __launch_bounds__(256) void numer_kernel(const float* __restrict__ em,
                                                    const int* __restrict__ tags,
                                                    const float* __restrict__ trans,
                                                    const float* __restrict__ start_trans,
                                                    const float* __restrict__ end_trans,
                                                    float* __restrict__ num) {
  const int b = blockIdx.x;
  const int tg = tags[b];
  float acc = 0.f;
  for (int t = threadIdx.x; t < TT; t += 256)
    acc += em[((size_t)t * BB + b) * NTAG + tg];
#pragma unroll
  for (int off = 32; off > 0; off >>= 1) acc += __shfl_xor(acc, off, 64);
  __shared__ float red[4];
  if ((threadIdx.x & 63) == 0) red[threadIdx.x >> 6] = acc;
  __syncthreads();
  if (threadIdx.x == 0) {
    const float tot = red[0] + red[1] + red[2] + red[3];
    num[b] = start_trans[tg] + end_trans[tg] + 1023.0f * trans[tg * NTAG + tg] + tot;
  }
}

// ---------------------------------------------------------------- final
__global__ __launch_bounds__(128) void final_kernel(const float* __restrict__ denom,
                                                    const float* __restrict__ num,
                                                    float* __restrict__ out) {
  const int tid = threadIdx.x;
  float v = denom[tid] - num[tid];
#pragma unroll
  for (int off = 32; off > 0; off >>= 1) v += __shfl_xor(v, off, 64);
  __shared__ float red[2];
  if ((tid & 63) == 0) red[tid >> 6] = v;
  __syncthreads();
  if (tid == 0) out[0] = red[0] + red[1];
}

extern "C" void kernel_launch(void* const* d_in, const int* in_sizes, int n_in,
                              void* d_out, int out_size, void* d_ws, size_t ws_size,
                              hipStream_t stream) {
  const int* kmers = (const int*)d_in[0];
  const int* tags = (const int*)d_in[1];
  const float* emb = (const float*)d_in[2];
  const float* w_ih_f = (const float*)d_in[3];
  const float* w_hh_f = (const float*)d_in[4];
  const float* b_ih_f = (const float*)d_in[5];
  const float* b_hh_f = (const float*)d_in[6];
  const float* w_ih_b = (const float*)d_in[7];
  const float* w_hh_b = (const float*)d_in[8];
  const float* b_ih_b = (const float*)d_in[9];
  const float* b_hh_b = (const float*)d_in[10];
  const float* w_proj = (const float*)d_in[11];
  const float* b_proj = (const float*)d_in[12];
  const float* start_trans = (const float*)d_in[13];
  const float* end_trans = (const float*)d_in[14];
  const float* trans = (const float*)d_in[15];

  int nseg;
  if (ws_size >= 235078656ull) nseg = 2;
  else if (ws_size >= 167969792ull) nseg = 4;
  else if (ws_size >= 134415360ull) nseg = 8;
  else nseg = 16;
  const int Tseg = TT / nseg;
  const size_t xg_bytes = 268435456ull / (size_t)nseg;

  char* ws = (char*)d_ws;
  half4_t* x = (half4_t*)ws;                       // [0, 33.5M); em aliases after xg done
  _Float16* h_cat = (_Float16*)(ws + 33554432);    // [33.5M, 100.7M)
  _Float16* xgbuf = (_Float16*)(ws + 100663296);   // [100.7M, +xg_bytes)
  _Float16* expem = (_Float16*)(ws + 100663296);   // 16.8M, aliases xgbuf (dead after lstm)
  _Float16* h_state = (_Float16*)(ws + 100663296 + xg_bytes);    // 65,536 B
  float* c_state = (float*)(ws + 100663296 + xg_bytes + 65536);  // 131,072 B
  float* denom = (float*)(ws + 100663296 + xg_bytes + 196608);   // 512 B
  float* num = denom + 128;
  float* em = (float*)ws;
  float* out = (float*)d_out;

  hipLaunchKernelGGL(init_kernel, dim3(48), dim3(256), 0, stream, (float4_t*)h_state);
  hipLaunchKernelGGL(embed_kernel, dim3(16384), dim3(256), 0, stream, kmers, emb, x);
  for (int s = 0; s < nseg; ++s) {
    hipLaunchKernelGGL(xg_kernel, dim3(Tseg), dim3(512), 0, stream, (const _Float16*)x,
                       w_ih_f, b_ih_f, b_hh_f, w_ih_b, b_ih_b, b_hh_b, xgbuf, s, Tseg);
    hipLaunchKernelGGL(lstm_kernel, dim3(16), dim3(512), 0, stream, (const _Float16*)xgbuf,
                       w_hh_f, w_hh_b, h_cat, h_state, c_state, s, Tseg);
  }
  hipLaunchKernelGGL(emis_kernel, dim3(2048), dim3(256), 0, stream, h_cat, w_proj, b_proj, em,
                     expem);
  hipLaunchKernelGGL(crf_kernel, dim3(32), dim3(64), 0, stream, em, (const _Float16*)expem,
                     trans, start_trans, end_trans, denom);
  hipLaunchKernelGGL(numer_kernel, dim3(128), dim3(256), 0, stream, em, tags, trans, start_trans,
                     end_trans, num);
  hipLaunchKernelGGL(final_kernel, dim3(1), dim3(128), 0, stream, denom, num, out);
}